// Round 1
// baseline (1259.139 us; speedup 1.0000x reference)
//
#include <hip/hip_runtime.h>
#include <math.h>

// ---------------------------------------------------------------------------
// PrimitiveLibrary: 6 primitives on a 4096-dim state, all matvec-shaped.
// HBM-bound: 1.644 GB of fp32 weights per call -> ~260us floor at 6.3 TB/s.
// Structure: 3 fused "job table" matvec kernels (one wave per row) + 1 tiny
// LN/attn kernel + 1 combine kernel. 5 launches on `stream`.
// ---------------------------------------------------------------------------

#define SD 4096

__device__ __forceinline__ float gelu_erf(float x) {
    return 0.5f * x * (1.0f + erff(x * 0.70710678118654752f));
}

struct Job {
    const float* W;       // M x N row-major
    const float* xa;      // x for columns [0, nsplit)
    const float* xb;      // x for columns [nsplit, N)
    const float* bias;    // M
    const float* xscale;  // optional scalar (device ptr), nullptr => 1.0
    float*       y;       // M
    int M, N, nsplit, act, rowstart, pad;
};

struct JobPack {
    Job jobs[8];
    int njobs;
    int pad;
};

// One wave (64 lanes) per output row; 4 rows per 256-thread block.
__global__ __launch_bounds__(256) void matvec_multi(JobPack P) {
    const int rowbase = blockIdx.x * 4;

    // find job (rowstart ascending) -- uniform per block
    int ji = 0;
#pragma unroll
    for (int t = 1; t < 8; ++t)
        if (t < P.njobs && rowbase >= P.jobs[t].rowstart) ji = t;

    const Job j = P.jobs[ji];

    const int wave = threadIdx.x >> 6;
    const int lane = threadIdx.x & 63;
    const int row  = rowbase - j.rowstart + wave;
    if (row >= j.M) return;

    const float* __restrict__ Wr = j.W + (size_t)row * (size_t)j.N;

    float acc = 0.0f;
#pragma unroll 4
    for (int c = lane * 4; c < j.N; c += 256) {
        const float4 wv = *(const float4*)(Wr + c);
        float4 xv;
        if (c < j.nsplit) xv = *(const float4*)(j.xa + c);
        else              xv = *(const float4*)(j.xb + (c - j.nsplit));
        acc += wv.x * xv.x + wv.y * xv.y + wv.z * xv.z + wv.w * xv.w;
    }

    // wave-64 reduction
#pragma unroll
    for (int off = 32; off; off >>= 1)
        acc += __shfl_down(acc, off, 64);

    if (lane == 0) {
        float scale = j.xscale ? *j.xscale : 1.0f;
        float r = acc * scale + j.bias[row];
        if (j.act == 1)      r = tanhf(r);
        else if (j.act == 2) r = gelu_erf(r);
        j.y[row] = r;
    }
}

// Block 0: LayerNorm (4096) + GELU into mor_act.  Block 1: attn scalar.
__global__ __launch_bounds__(256) void small_ops(
        const float* __restrict__ h_mor, const float* __restrict__ mor_g,
        const float* __restrict__ mor_beta, float* __restrict__ mor_act,
        const float* __restrict__ q, const float* __restrict__ k,
        float* __restrict__ sig) {
    __shared__ float sb[256];
    const int tid = threadIdx.x;

    if (blockIdx.x == 0) {
        float v[16];
        float s = 0.0f;
#pragma unroll
        for (int i = 0; i < 16; ++i) {
            v[i] = h_mor[tid + 256 * i];
            s += v[i];
        }
        sb[tid] = s;
        __syncthreads();
        for (int o = 128; o; o >>= 1) {
            if (tid < o) sb[tid] += sb[tid + o];
            __syncthreads();
        }
        const float mu = sb[0] * (1.0f / 4096.0f);
        __syncthreads();

        float ss = 0.0f;
#pragma unroll
        for (int i = 0; i < 16; ++i) {
            const float d = v[i] - mu;
            ss += d * d;
        }
        sb[tid] = ss;
        __syncthreads();
        for (int o = 128; o; o >>= 1) {
            if (tid < o) sb[tid] += sb[tid + o];
            __syncthreads();
        }
        const float var = sb[0] * (1.0f / 4096.0f);
        const float rs = rsqrtf(var + 1e-5f);
#pragma unroll
        for (int i = 0; i < 16; ++i) {
            const int idx = tid + 256 * i;
            const float t = (v[i] - mu) * rs * mor_g[idx] + mor_beta[idx];
            mor_act[idx] = gelu_erf(t);
        }
    } else {
        float s = 0.0f;
        for (int i = tid; i < 1024; i += 256) s += q[i] * k[i];
        sb[tid] = s;
        __syncthreads();
        for (int o = 128; o; o >>= 1) {
            if (tid < o) sb[tid] += sb[tid + o];
            __syncthreads();
        }
        if (tid == 0) {
            const float attn = sb[0] * (1.0f / 32.0f);  // / sqrt(1024)
            *sig = 1.0f / (1.0f + expf(-attn));
        }
    }
}

__global__ __launch_bounds__(256) void combine(
        const float* __restrict__ w, const float* __restrict__ gates,
        const float* __restrict__ s,
        const float* __restrict__ d0, const float* __restrict__ d1,
        const float* __restrict__ d2, const float* __restrict__ d3,
        const float* __restrict__ d4, const float* __restrict__ d5,
        float* __restrict__ out) {
    const int i = blockIdx.x * 256 + threadIdx.x;
    if (i >= SD) return;
    const float si = s[i];
    float acc = 0.0f;
    const float* ds[6] = {d0, d1, d2, d3, d4, d5};
#pragma unroll
    for (int p = 0; p < 6; ++p) {
        const float gp = 1.0f / (1.0f + expf(-gates[p]));
        acc += w[p] * (si + gp * ds[p][i]);
    }
    out[i] = acc;
}

extern "C" void kernel_launch(void* const* d_in, const int* in_sizes, int n_in,
                              void* d_out, int out_size, void* d_ws, size_t ws_size,
                              hipStream_t stream) {
    const float* weights   = (const float*)d_in[0];
    const float* state     = (const float*)d_in[1];
    const float* id_w      = (const float*)d_in[2];
    const float* id_b      = (const float*)d_in[3];
    const float* neg_w1    = (const float*)d_in[4];
    const float* neg_b1    = (const float*)d_in[5];
    const float* neg_w2    = (const float*)d_in[6];
    const float* neg_b2    = (const float*)d_in[7];
    const float* neg_w3    = (const float*)d_in[8];
    const float* neg_b3    = (const float*)d_in[9];
    const float* mor_w1    = (const float*)d_in[10];
    const float* mor_b1    = (const float*)d_in[11];
    const float* mor_g     = (const float*)d_in[12];
    const float* mor_beta  = (const float*)d_in[13];
    const float* mor_w2    = (const float*)d_in[14];
    const float* mor_b2    = (const float*)d_in[15];
    const float* aq_w      = (const float*)d_in[16];
    const float* aq_b      = (const float*)d_in[17];
    const float* ak_w      = (const float*)d_in[18];
    const float* ak_b      = (const float*)d_in[19];
    const float* av_w      = (const float*)d_in[20];
    const float* av_b      = (const float*)d_in[21];
    const float* ao_w      = (const float*)d_in[22];
    const float* ao_b      = (const float*)d_in[23];
    const float* lk_w1     = (const float*)d_in[24];
    const float* lk_b1     = (const float*)d_in[25];
    const float* lk_w2     = (const float*)d_in[26];
    const float* lk_b2     = (const float*)d_in[27];
    const float* lk_w3     = (const float*)d_in[28];
    const float* lk_b3     = (const float*)d_in[29];
    const float* blend_ctx = (const float*)d_in[30];
    const float* bl_w1     = (const float*)d_in[31];
    const float* bl_b1     = (const float*)d_in[32];
    const float* bl_w2     = (const float*)d_in[33];
    const float* bl_b2     = (const float*)d_in[34];
    const float* gates     = (const float*)d_in[35];

    float* ws = (float*)d_ws;
    float* h_neg1  = ws + 0;       // 8192
    float* h_neg2  = ws + 8192;    // 8192
    float* h_lk1   = ws + 16384;   // 8192
    float* h_lk2   = ws + 24576;   // 8192
    float* h_mor   = ws + 32768;   // 4096
    float* mor_act = ws + 36864;   // 4096
    float* q       = ws + 40960;   // 1024
    float* kk      = ws + 41984;   // 1024
    float* v       = ws + 43008;   // 4096
    float* sig     = ws + 47104;   // 1 (padded)
    float* h_bl    = ws + 47360;   // 4096
    float* d0      = ws + 51456;   // 4096
    float* d1      = ws + 55552;
    float* d2      = ws + 59648;
    float* d3      = ws + 63744;
    float* d4      = ws + 67840;
    float* d5      = ws + 71936;   // ends at 76032 floats (~304 KB)

    // ---------------- Stage A: everything that depends only on `state` -----
    JobPack A = {};
    A.njobs = 8;
    int rs = 0;
    // {W, xa, xb, bias, xscale, y, M, N, nsplit, act, rowstart}
    A.jobs[0] = {id_w,   state, state,     id_b,   nullptr, d0,     SD,     SD,     SD,     1, rs, 0}; rs += SD;
    A.jobs[1] = {neg_w1, state, state,     neg_b1, nullptr, h_neg1, 2*SD,   SD,     SD,     2, rs, 0}; rs += 2*SD;
    A.jobs[2] = {mor_w1, state, state,     mor_b1, nullptr, h_mor,  SD,     SD,     SD,     0, rs, 0}; rs += SD;
    A.jobs[3] = {aq_w,   state, state,     aq_b,   nullptr, q,      SD/4,   SD,     SD,     0, rs, 0}; rs += SD/4;
    A.jobs[4] = {ak_w,   state, state,     ak_b,   nullptr, kk,     SD/4,   SD,     SD,     0, rs, 0}; rs += SD/4;
    A.jobs[5] = {av_w,   state, state,     av_b,   nullptr, v,      SD,     SD,     SD,     0, rs, 0}; rs += SD;
    A.jobs[6] = {lk_w1,  state, state,     lk_b1,  nullptr, h_lk1,  2*SD,   SD,     SD,     2, rs, 0}; rs += 2*SD;
    A.jobs[7] = {bl_w1,  state, blend_ctx, bl_b1,  nullptr, h_bl,   SD,     2*SD,   SD,     2, rs, 0}; rs += SD;
    const int blocksA = rs / 4;  // 8704
    matvec_multi<<<blocksA, 256, 0, stream>>>(A);

    // ---------------- LN stats+apply, attn scalar --------------------------
    small_ops<<<2, 256, 0, stream>>>(h_mor, mor_g, mor_beta, mor_act, q, kk, sig);

    // ---------------- Stage B ---------------------------------------------
    JobPack B = {};
    B.njobs = 5;
    rs = 0;
    B.jobs[0] = {neg_w2, h_neg1,  h_neg1,  neg_b2, nullptr, h_neg2, 2*SD, 2*SD, 2*SD, 2, rs, 0}; rs += 2*SD;
    B.jobs[1] = {mor_w2, mor_act, mor_act, mor_b2, nullptr, d2,     SD,   SD,   SD,   0, rs, 0}; rs += SD;
    B.jobs[2] = {ao_w,   v,       v,       ao_b,   sig,     d3,     SD,   SD,   SD,   0, rs, 0}; rs += SD;
    B.jobs[3] = {lk_w2,  h_lk1,   h_lk1,   lk_b2,  nullptr, h_lk2,  2*SD, 2*SD, 2*SD, 2, rs, 0}; rs += 2*SD;
    B.jobs[4] = {bl_w2,  h_bl,    h_bl,    bl_b2,  nullptr, d5,     SD,   SD,   SD,   0, rs, 0}; rs += SD;
    const int blocksB = rs / 4;  // 7168
    matvec_multi<<<blocksB, 256, 0, stream>>>(B);

    // ---------------- Stage C ---------------------------------------------
    JobPack C = {};
    C.njobs = 2;
    rs = 0;
    C.jobs[0] = {neg_w3, h_neg2, h_neg2, neg_b3, nullptr, d1, SD, 2*SD, 2*SD, 0, rs, 0}; rs += SD;
    C.jobs[1] = {lk_w3,  h_lk2,  h_lk2,  lk_b3,  nullptr, d4, SD, 2*SD, 2*SD, 0, rs, 0}; rs += SD;
    const int blocksC = rs / 4;  // 2048
    matvec_multi<<<blocksC, 256, 0, stream>>>(C);

    // ---------------- Combine ---------------------------------------------
    combine<<<SD / 256, 256, 0, stream>>>(weights, gates, state,
                                          d0, d1, d2, d3, d4, d5, (float*)d_out);
}